// Round 2
// baseline (320.924 us; speedup 1.0000x reference)
//
#include <hip/hip_runtime.h>
#include <hip/hip_bf16.h>

typedef __hip_bfloat16 bf16;

// Node-axis collapse: cur starts as broadcast of z over the 128 nodes, and all
// ops (dense over channels, parent-gather of identical columns, pointwise,
// BN over (n,nodes)) are node-independent -> p0..p4 are dead, the whole net is
// a per-sample chain of tiny dense layers, output = tanh(h4[n,0]) broadcast
// over 67615 columns.
//
// Dtype is detected at runtime on-device (flag in d_ws[32]): decode low 16 bits
// of the first 64 words of z as bf16; bf16 storage -> real z samples (sane),
// f32 storage -> random mantissa bits (virtually never all sane).

__device__ __forceinline__ float ldf(const void* p, int i, int isbf) {
  if (isbf) return __bfloat162float(((const bf16*)p)[i]);
  return ((const float*)p)[i];
}

struct Params {
  const void* z;
  const int *sv, *tv, *cv;
  const void *se, *te, *ce;
  const void *fcw[5], *fcb[5];
  const void *w[5],  *wb[5];
  const void *g[4],  *be[4];
  float* t;   // d_ws: t[0..31], flag at ((int*)t)[32]
};

#define NTHREADS 512

template<int INC, int OUT, int FCIN, int INSTRIDE>
__device__ __forceinline__ void do_level(
    int tid, int isbf,
    const float* curin, float* curout, float* h, float* cont,
    const float* cat, float* A, float* Bv,
    const void* fcw, const void* fcb,
    const void* W, const void* Wb,
    const void* g, const void* be)
{
  // contents[n][c] = (cat[:, :FCIN] @ fcw)[n,c] + fcb[c]
  for (int i = tid; i < 32 * 16; i += NTHREADS) {
    int n = i >> 4, c = i & 15;
    float s = ldf(fcb, c, isbf);
#pragma unroll
    for (int k = 0; k < FCIN; k++) s += cat[n * 48 + k] * ldf(fcw, k * 16 + c, isbf);
    cont[i] = s;
  }
  __syncthreads();
  // h[n][o] = W[o,:INC].cur[n] + W[o,INC:].cont[n] + Wb[o]; leaky relu
  for (int i = tid; i < 32 * OUT; i += NTHREADS) {
    int n = i / OUT, o = i % OUT;
    const int wr = o * (INC + 16);
    float s = ldf(Wb, o, isbf);
    const float* xr = curin + n * INSTRIDE;
#pragma unroll 8
    for (int c = 0; c < INC; c++) s += xr[c] * ldf(W, wr + c, isbf);
    const float* cr = cont + n * 16;
#pragma unroll
    for (int k = 0; k < 16; k++) s += cr[k] * ldf(W, wr + INC + k, isbf);
    s = (s >= 0.f) ? s : 0.2f * s;
    h[n * 64 + o] = s;
  }
  __syncthreads();
  // BN stats over n (population var)
  if (tid < OUT) {
    int o = tid;
    float su = 0.f, sq = 0.f;
#pragma unroll
    for (int n = 0; n < 32; n++) { float v = h[n * 64 + o]; su += v; sq += v * v; }
    float mean = su * (1.f / 32.f);
    float var  = fmaxf(sq * (1.f / 32.f) - mean * mean, 0.f);
    float inv  = rsqrtf(var + 1e-5f);
    float a = ldf(g, o, isbf) * inv;
    A[o]  = a;
    Bv[o] = ldf(be, o, isbf) - mean * a;
  }
  __syncthreads();
  for (int i = tid; i < 32 * OUT; i += NTHREADS) {
    int n = i / OUT, o = i % OUT;
    curout[n * 64 + o] = A[o] * h[n * 64 + o] + Bv[o];
  }
  __syncthreads();
}

__global__ __launch_bounds__(NTHREADS) void head_kernel(Params P) {
  __shared__ float zl[32 * 128];
  __shared__ float cat[32 * 48];
  __shared__ float cont[32 * 16];
  __shared__ float h[32 * 64];
  __shared__ float curb[32 * 64];
  __shared__ float A[64], Bv[64];
  __shared__ int sISBF;
  int tid = threadIdx.x;

  if (tid == 0) {
    const unsigned int* w = (const unsigned int*)P.z;
    int allsane = 1;
    for (int i = 0; i < 64; i++) {
      unsigned short lo = (unsigned short)(w[i] & 0xFFFFu);
      bf16 bv = __builtin_bit_cast(bf16, lo);
      float a = fabsf(__bfloat162float(bv));
      if (!(a == 0.0f || (a >= 1e-12f && a <= 1e4f))) allsane = 0;
    }
    sISBF = allsane;
    ((int*)P.t)[32] = allsane;   // tell bcast_kernel the dtype
  }
  __syncthreads();
  const int isbf = sISBF;

  for (int i = tid; i < 32 * 128; i += NTHREADS) zl[i] = ldf(P.z, i, isbf);
  for (int i = tid; i < 32 * 16; i += NTHREADS) {
    int n = i >> 4, c = i & 15;
    cat[n * 48 + c]      = ldf(P.se, P.sv[n] * 16 + c, isbf);
    cat[n * 48 + 16 + c] = ldf(P.te, P.tv[n] * 16 + c, isbf);
    cat[n * 48 + 32 + c] = ldf(P.ce, P.cv[n] * 16 + c, isbf);
  }
  __syncthreads();

  do_level<128, 64, 16, 128>(tid, isbf, zl,   curb, h, cont, cat, A, Bv,
                             P.fcw[0], P.fcb[0], P.w[0], P.wb[0], P.g[0], P.be[0]);
  do_level< 64, 32, 32,  64>(tid, isbf, curb, curb, h, cont, cat, A, Bv,
                             P.fcw[1], P.fcb[1], P.w[1], P.wb[1], P.g[1], P.be[1]);
  do_level< 32, 16, 48,  64>(tid, isbf, curb, curb, h, cont, cat, A, Bv,
                             P.fcw[2], P.fcb[2], P.w[2], P.wb[2], P.g[2], P.be[2]);
  do_level< 16,  8, 48,  64>(tid, isbf, curb, curb, h, cont, cat, A, Bv,
                             P.fcw[3], P.fcb[3], P.w[3], P.wb[3], P.g[3], P.be[3]);

  // level 4: contents via fc4 (48-in), OUT=1, tanh, no BN
  for (int i = tid; i < 32 * 16; i += NTHREADS) {
    int n = i >> 4, c = i & 15;
    float s = ldf(P.fcb[4], c, isbf);
#pragma unroll
    for (int k = 0; k < 48; k++) s += cat[n * 48 + k] * ldf(P.fcw[4], k * 16 + c, isbf);
    cont[i] = s;
  }
  __syncthreads();
  if (tid < 32) {
    int n = tid;
    float s = ldf(P.wb[4], 0, isbf);
#pragma unroll
    for (int c = 0; c < 8; c++) s += curb[n * 64 + c] * ldf(P.w[4], c, isbf);
#pragma unroll
    for (int k = 0; k < 16; k++) s += cont[n * 16 + k] * ldf(P.w[4], 8 + k, isbf);
    P.t[n] = tanhf(s);
  }
}

#define ROW 67615

// out[n*ROW + j] = t[n] for all j, in the detected output dtype.
// Row strides are not 16B-aligned; per-row alignment shift + 16B interior
// stores; block (0,n) thread 0 mops up head+tail scalars.
__global__ __launch_bounds__(256) void bcast_kernel(const float* __restrict__ t,
                                                    void* __restrict__ outv) {
  int n = blockIdx.y;
  int isbf = ((const int*)t)[32];
  float tv = t[n];
  int chunk = blockIdx.x * 256 + threadIdx.x;

  if (isbf) {
    bf16 hv = __float2bfloat16(tv);
    unsigned short us = __builtin_bit_cast(unsigned short, hv);
    unsigned int u2 = ((unsigned int)us << 16) | (unsigned int)us;
    uint4 v4 = make_uint4(u2, u2, u2, u2);
    unsigned short* row = (unsigned short*)outv + (size_t)n * ROW;
    int s = (int)((16u - ((unsigned int)(unsigned long long)row & 15u)) & 15u) >> 1;
    int e = s + chunk * 8;
    if (e + 8 <= ROW) *(uint4*)(row + e) = v4;
    if (blockIdx.x == 0 && threadIdx.x == 0) {
      for (int i = 0; i < s; i++) row[i] = us;
      int nch = (ROW - s) >> 3;
      for (int i = s + nch * 8; i < ROW; i++) row[i] = us;
    }
  } else {
    float* row = (float*)outv + (size_t)n * ROW;
    int s = (int)((16u - ((unsigned int)(unsigned long long)row & 15u)) & 15u) >> 2;
    int e = s + chunk * 4;
    if (e + 4 <= ROW) *(float4*)(row + e) = make_float4(tv, tv, tv, tv);
    if (blockIdx.x == 0 && threadIdx.x == 0) {
      for (int i = 0; i < s; i++) row[i] = tv;
      int nch = (ROW - s) >> 2;
      for (int i = s + nch * 4; i < ROW; i++) row[i] = tv;
    }
  }
}

extern "C" void kernel_launch(void* const* d_in, const int* in_sizes, int n_in,
                              void* d_out, int out_size, void* d_ws, size_t ws_size,
                              hipStream_t stream) {
  Params P;
  P.z  = d_in[0];
  P.sv = (const int*)d_in[1];
  P.tv = (const int*)d_in[2];
  P.cv = (const int*)d_in[3];
  P.se = d_in[4];
  P.te = d_in[5];
  P.ce = d_in[6];
  for (int i = 0; i < 5; i++) {
    P.fcw[i] = d_in[7 + 2 * i];
    P.fcb[i] = d_in[8 + 2 * i];
  }
  for (int i = 0; i < 5; i++) {
    P.w[i]  = d_in[17 + 2 * i];
    P.wb[i] = d_in[18 + 2 * i];
  }
  for (int i = 0; i < 4; i++) {
    P.g[i]  = d_in[27 + 2 * i];
    P.be[i] = d_in[28 + 2 * i];
  }
  // p0..p4 (d_in[35..39]) are provably dead (node axis carries no information).
  P.t = (float*)d_ws;

  hipLaunchKernelGGL(head_kernel, dim3(1), dim3(NTHREADS), 0, stream, P);
  // grid.x = 67 covers the f32 path (ceil(67615/4/256)); bf16 path needs 34,
  // extra blocks fall out of the guard.
  hipLaunchKernelGGL(bcast_kernel, dim3(67, 32), dim3(256), 0, stream,
                     (const float*)d_ws, d_out);
}

// Round 3
// 160.706 us; speedup vs baseline: 1.9970x; 1.9970x over previous
//
#include <hip/hip_runtime.h>
#include <hip/hip_bf16.h>

typedef __hip_bfloat16 bf16;
#define NT 512
#define ROW 67615

// Node-axis collapse: cur starts as a broadcast of z over the 128 nodes; every
// op (dense over channels, parent-gather of identical columns, pointwise, BN
// over (n,nodes)) is node-independent -> p0..p4 dead, net collapses to a
// per-sample chain of tiny dense layers; out = tanh(h4[n,0]) broadcast.
//
// Dtype detected on-device (flag in d_ws[32]). All compute from LDS:
// activations f32, weights staged per-level as bf16 (<=0.4% rel rounding;
// lossless when inputs are bf16). Strides padded for conflict-free LDS reads.

__device__ __forceinline__ float bs2f(unsigned short u) {
  unsigned int w = ((unsigned int)u) << 16;
  return __builtin_bit_cast(float, w);
}

__device__ __forceinline__ float gld(const void* p, int i, int isbf) {
  if (isbf) return bs2f(((const unsigned short*)p)[i]);
  return ((const float*)p)[i];
}

__device__ __forceinline__ void stage_us(unsigned short* dst, const void* src,
                                         int len, int isbf, int tid) {
  if (isbf) {
    const unsigned short* s = (const unsigned short*)src;
    for (int i = tid; i < len; i += NT) dst[i] = s[i];
  } else {
    const float* s = (const float*)src;
    for (int i = tid; i < len; i += NT)
      dst[i] = __builtin_bit_cast(unsigned short, __float2bfloat16(s[i]));
  }
}

__device__ __forceinline__ void stage_us_pad(unsigned short* dst, const void* src,
                                             int rows, int cols, int stride,
                                             int isbf, int tid) {
  int len = rows * cols;
  if (isbf) {
    const unsigned short* s = (const unsigned short*)src;
    for (int i = tid; i < len; i += NT) dst[(i / cols) * stride + (i % cols)] = s[i];
  } else {
    const float* s = (const float*)src;
    for (int i = tid; i < len; i += NT)
      dst[(i / cols) * stride + (i % cols)] =
          __builtin_bit_cast(unsigned short, __float2bfloat16(s[i]));
  }
}

struct Params {
  const void* z;
  const int *sv, *tv, *cv;
  const void *se, *te, *ce;
  const void *fcw[5], *fcb[5];
  const void *w[5],  *wb[5];
  const void *g[4],  *be[4];
  float* t;   // d_ws: t[0..31], dtype flag at ((int*)t)[32]
};

// wl layout per level: fcw[FCIN*16] | fcb[16] | W[OUT x WS] | wb[OUT] | g[OUT] | be[OUT]
template<int INC, int OUT, int FCIN, int INSTRIDE, int WS>
__device__ __forceinline__ void do_level(
    int tid, int isbf, const float* curin, float* curout,
    float* cont, const float* cat, float* A, float* Bv,
    unsigned short* wl,
    const void* fcw, const void* fcb, const void* W, const void* Wb,
    const void* g, const void* be)
{
  constexpr int OFF_FCB = FCIN * 16;
  constexpr int OFF_W   = OFF_FCB + 16;
  constexpr int OFF_WB  = OFF_W + OUT * WS;
  constexpr int OFF_G   = OFF_WB + OUT;
  constexpr int OFF_BE  = OFF_G + OUT;

  // Stage this level's params (prev level's wl reads finished before its last sync)
  stage_us(wl,           fcw, FCIN * 16, isbf, tid);
  stage_us(wl + OFF_FCB, fcb, 16,        isbf, tid);
  stage_us_pad(wl + OFF_W, W, OUT, INC + 16, WS, isbf, tid);
  stage_us(wl + OFF_WB,  Wb,  OUT, isbf, tid);
  stage_us(wl + OFF_G,   g,   OUT, isbf, tid);
  stage_us(wl + OFF_BE,  be,  OUT, isbf, tid);
  __syncthreads();

  // contents[n][c] = cat[n,:FCIN] @ fcw + fcb[c]
  for (int i = tid; i < 512; i += NT) {
    int n = i >> 4, c = i & 15;
    float s = bs2f(wl[OFF_FCB + c]);
#pragma unroll
    for (int k = 0; k < FCIN; k++) s += cat[n * 48 + k] * bs2f(wl[k * 16 + c]);
    cont[n * 17 + c] = s;
  }
  __syncthreads();

  // h = leaky(W @ [cur; cont] + wb), 2x2 (n x o) register tile
  constexpr int TO = OUT / 2;
  constexpr int NTILES = 16 * TO;
  for (int i = tid; i < NTILES; i += NT) {
    int tn = i / TO, to = i % TO;
    int n0 = 2 * tn, o0 = 2 * to;
    const unsigned short* w0 = wl + OFF_W + o0 * WS;
    const unsigned short* w1 = w0 + WS;
    const float* x0 = curin + n0 * INSTRIDE;
    const float* x1 = x0 + INSTRIDE;
    float b0 = bs2f(wl[OFF_WB + o0]), b1 = bs2f(wl[OFF_WB + o0 + 1]);
    float s00 = b0, s01 = b1, s10 = b0, s11 = b1;
#pragma unroll 8
    for (int c = 0; c < INC; c++) {
      float xa = x0[c], xb = x1[c];
      float wa = bs2f(w0[c]), wc = bs2f(w1[c]);
      s00 += xa * wa; s01 += xa * wc; s10 += xb * wa; s11 += xb * wc;
    }
    const float* c0 = cont + n0 * 17;
    const float* c1 = c0 + 17;
#pragma unroll
    for (int k = 0; k < 16; k++) {
      float xa = c0[k], xb = c1[k];
      float wa = bs2f(w0[INC + k]), wc = bs2f(w1[INC + k]);
      s00 += xa * wa; s01 += xa * wc; s10 += xb * wa; s11 += xb * wc;
    }
    s00 = s00 >= 0.f ? s00 : 0.2f * s00;
    s01 = s01 >= 0.f ? s01 : 0.2f * s01;
    s10 = s10 >= 0.f ? s10 : 0.2f * s10;
    s11 = s11 >= 0.f ? s11 : 0.2f * s11;
    curout[n0 * 65 + o0]           = s00;
    curout[n0 * 65 + o0 + 1]       = s01;
    curout[(n0 + 1) * 65 + o0]     = s10;
    curout[(n0 + 1) * 65 + o0 + 1] = s11;
  }
  __syncthreads();

  // BN stats over n (population var), in-place normalize
  if (tid < OUT) {
    int o = tid;
    float su = 0.f, sq = 0.f;
#pragma unroll
    for (int n = 0; n < 32; n++) { float v = curout[n * 65 + o]; su += v; sq += v * v; }
    float mean = su * (1.f / 32.f);
    float var  = fmaxf(sq * (1.f / 32.f) - mean * mean, 0.f);
    float inv  = rsqrtf(var + 1e-5f);
    float a = bs2f(wl[OFF_G + o]) * inv;
    A[o]  = a;
    Bv[o] = bs2f(wl[OFF_BE + o]) - mean * a;
  }
  __syncthreads();
  for (int i = tid; i < 32 * OUT; i += NT) {
    int n = i / OUT, o = i % OUT;
    curout[n * 65 + o] = A[o] * curout[n * 65 + o] + Bv[o];
  }
  __syncthreads();
}

__global__ __launch_bounds__(NT) void head_kernel(Params P) {
  __shared__ float zl[32 * 128];
  __shared__ float cat[32 * 48];
  __shared__ float cont[32 * 17];
  __shared__ float act0[32 * 65];
  __shared__ float act1[32 * 65];
  __shared__ float A[64], Bv[64];
  __shared__ unsigned short wl[9856];
  __shared__ int sOK;
  int tid = threadIdx.x;

  // dtype detect: decode low 16 bits of first 64 words of z as bf16
  if (tid == 0) sOK = 1;
  __syncthreads();
  if (tid < 64) {
    unsigned int w = ((const unsigned int*)P.z)[tid];
    float a = fabsf(bs2f((unsigned short)(w & 0xFFFFu)));
    if (!(a == 0.0f || (a >= 1e-12f && a <= 1e4f))) atomicAnd(&sOK, 0);
  }
  __syncthreads();
  const int isbf = sOK;
  if (tid == 0) ((int*)P.t)[32] = isbf;

  // stage z (f32, no precision loss) and cat gathers
  if (isbf) {
    const unsigned short* s = (const unsigned short*)P.z;
    for (int i = tid; i < 4096; i += NT) zl[i] = bs2f(s[i]);
  } else {
    const float* s = (const float*)P.z;
    for (int i = tid; i < 4096; i += NT) zl[i] = s[i];
  }
  for (int i = tid; i < 512; i += NT) {
    int n = i >> 4, c = i & 15;
    cat[n * 48 + c]      = gld(P.se, P.sv[n] * 16 + c, isbf);
    cat[n * 48 + 16 + c] = gld(P.te, P.tv[n] * 16 + c, isbf);
    cat[n * 48 + 32 + c] = gld(P.ce, P.cv[n] * 16 + c, isbf);
  }
  // do_level stages wl then syncs before any read; zl/cat reads happen after that sync

  do_level<128, 64, 16, 128, 146>(tid, isbf, zl,   act0, cont, cat, A, Bv, wl,
      P.fcw[0], P.fcb[0], P.w[0], P.wb[0], P.g[0], P.be[0]);
  do_level< 64, 32, 32,  65,  98>(tid, isbf, act0, act1, cont, cat, A, Bv, wl,
      P.fcw[1], P.fcb[1], P.w[1], P.wb[1], P.g[1], P.be[1]);
  do_level< 32, 16, 48,  65,  66>(tid, isbf, act1, act0, cont, cat, A, Bv, wl,
      P.fcw[2], P.fcb[2], P.w[2], P.wb[2], P.g[2], P.be[2]);
  do_level< 16,  8, 48,  65,  50>(tid, isbf, act0, act1, cont, cat, A, Bv, wl,
      P.fcw[3], P.fcb[3], P.w[3], P.wb[3], P.g[3], P.be[3]);

  // level 4: contents via fc4 (48-in), OUT=1, tanh, no BN
  stage_us(wl,       P.fcw[4], 768, isbf, tid);
  stage_us(wl + 768, P.fcb[4], 16,  isbf, tid);
  stage_us(wl + 784, P.w[4],   24,  isbf, tid);
  stage_us(wl + 808, P.wb[4],  1,   isbf, tid);
  __syncthreads();
  for (int i = tid; i < 512; i += NT) {
    int n = i >> 4, c = i & 15;
    float s = bs2f(wl[768 + c]);
#pragma unroll
    for (int k = 0; k < 48; k++) s += cat[n * 48 + k] * bs2f(wl[k * 16 + c]);
    cont[n * 17 + c] = s;
  }
  __syncthreads();
  if (tid < 32) {
    int n = tid;
    float s = bs2f(wl[808]);
#pragma unroll
    for (int c = 0; c < 8; c++) s += act1[n * 65 + c] * bs2f(wl[784 + c]);
#pragma unroll
    for (int k = 0; k < 16; k++) s += cont[n * 17 + k] * bs2f(wl[784 + 8 + k]);
    P.t[n] = tanhf(s);
  }
}

// out[n*ROW + j] = t[n] for all j, in the detected output dtype.
__global__ __launch_bounds__(256) void bcast_kernel(const float* __restrict__ t,
                                                    void* __restrict__ outv) {
  int n = blockIdx.y;
  int isbf = ((const int*)t)[32];
  float tv = t[n];
  int chunk = blockIdx.x * 256 + threadIdx.x;

  if (isbf) {
    bf16 hv = __float2bfloat16(tv);
    unsigned short us = __builtin_bit_cast(unsigned short, hv);
    unsigned int u2 = ((unsigned int)us << 16) | (unsigned int)us;
    uint4 v4 = make_uint4(u2, u2, u2, u2);
    unsigned short* row = (unsigned short*)outv + (size_t)n * ROW;
    int s = (int)((16u - ((unsigned int)(unsigned long long)row & 15u)) & 15u) >> 1;
    int e = s + chunk * 8;
    if (e + 8 <= ROW) *(uint4*)(row + e) = v4;
    if (blockIdx.x == 0 && threadIdx.x == 0) {
      for (int i = 0; i < s; i++) row[i] = us;
      int nch = (ROW - s) >> 3;
      for (int i = s + nch * 8; i < ROW; i++) row[i] = us;
    }
  } else {
    float* row = (float*)outv + (size_t)n * ROW;
    int s = (int)((16u - ((unsigned int)(unsigned long long)row & 15u)) & 15u) >> 2;
    int e = s + chunk * 4;
    if (e + 4 <= ROW) *(float4*)(row + e) = make_float4(tv, tv, tv, tv);
    if (blockIdx.x == 0 && threadIdx.x == 0) {
      for (int i = 0; i < s; i++) row[i] = tv;
      int nch = (ROW - s) >> 2;
      for (int i = s + nch * 4; i < ROW; i++) row[i] = tv;
    }
  }
}

extern "C" void kernel_launch(void* const* d_in, const int* in_sizes, int n_in,
                              void* d_out, int out_size, void* d_ws, size_t ws_size,
                              hipStream_t stream) {
  Params P;
  P.z  = d_in[0];
  P.sv = (const int*)d_in[1];
  P.tv = (const int*)d_in[2];
  P.cv = (const int*)d_in[3];
  P.se = d_in[4];
  P.te = d_in[5];
  P.ce = d_in[6];
  for (int i = 0; i < 5; i++) {
    P.fcw[i] = d_in[7 + 2 * i];
    P.fcb[i] = d_in[8 + 2 * i];
  }
  for (int i = 0; i < 5; i++) {
    P.w[i]  = d_in[17 + 2 * i];
    P.wb[i] = d_in[18 + 2 * i];
  }
  for (int i = 0; i < 4; i++) {
    P.g[i]  = d_in[27 + 2 * i];
    P.be[i] = d_in[28 + 2 * i];
  }
  // p0..p4 (d_in[35..39]) are provably dead (node axis carries no information).
  P.t = (float*)d_ws;

  hipLaunchKernelGGL(head_kernel, dim3(1), dim3(NT), 0, stream, P);
  // grid.x = 67 covers f32 (ceil(67615/4/256)); bf16 needs 34, extras guarded out.
  hipLaunchKernelGGL(bcast_kernel, dim3(67, 32), dim3(256), 0, stream,
                     (const float*)d_ws, d_out);
}

// Round 4
// 159.527 us; speedup vs baseline: 2.0117x; 1.0074x over previous
//
#include <hip/hip_runtime.h>
#include <hip/hip_bf16.h>

typedef __hip_bfloat16 bf16;
#define NT 512
#define ROW 67615

// Node-axis collapse: cur starts as a broadcast of z over the 128 nodes; every
// op is node-independent -> p0..p4 dead; net collapses to a per-sample chain of
// tiny dense layers; out = tanh(h4[n,0]) broadcast over 67615 columns.
//
// Dtype detected on-device (flag at ((int*)d_ws)[32]). All compute from LDS:
// f32 activations, weights staged as bf16 in a [c/4][o][4] panel layout so the
// MAC loop reads one ds_read_b128 per (o-pair x 4k) -> ~5x fewer LDS instrs
// than scalar. Strides: act 68, cont 20, cat 52 (16B-aligned, bank-spread).

__device__ __forceinline__ float lo16(unsigned int u) {
  return __builtin_bit_cast(float, u << 16);
}
__device__ __forceinline__ float hi16(unsigned int u) {
  return __builtin_bit_cast(float, u & 0xFFFF0000u);
}
__device__ __forceinline__ float bs2f(unsigned short u) {
  return __builtin_bit_cast(float, ((unsigned int)u) << 16);
}
__device__ __forceinline__ unsigned short f2bs(float f) {
  return __builtin_bit_cast(unsigned short, __float2bfloat16(f));
}
__device__ __forceinline__ float gld(const void* p, int i, int isbf) {
  if (isbf) return bs2f(((const unsigned short*)p)[i]);
  return ((const float*)p)[i];
}

// contiguous staging, scalar (only used for small arrays / fcw)
__device__ __forceinline__ void stage_us(unsigned short* dst, const void* src,
                                         int len, int isbf, int tid) {
  if (isbf) {
    const unsigned short* s = (const unsigned short*)src;
    for (int i = tid; i < len; i += NT) dst[i] = s[i];
  } else {
    const float* s = (const float*)src;
    for (int i = tid; i < len; i += NT) dst[i] = f2bs(s[i]);
  }
}

// W (row-major OUT x COLS in global) -> LDS panel [c4][o][4]
template<int OUT, int COLS>
__device__ __forceinline__ void stageW(unsigned short* dst, const void* src,
                                       int isbf, int tid) {
  constexpr int NC4 = COLS / 4;
  constexpr int TASKS = OUT * NC4;
  for (int j = tid; j < TASKS; j += NT) {
    int o = j % OUT, c4 = j / OUT;   // o fastest: conflict-free LDS writes
    ushort4 q;
    if (isbf) {
      q = *(const ushort4*)((const unsigned short*)src + o * COLS + 4 * c4);
    } else {
      float4 v = *(const float4*)((const float*)src + o * COLS + 4 * c4);
      q = make_ushort4(f2bs(v.x), f2bs(v.y), f2bs(v.z), f2bs(v.w));
    }
    *(ushort4*)(dst + (c4 * OUT + o) * 4) = q;
  }
}

struct Params {
  const void* z;
  const int *sv, *tv, *cv;
  const void *se, *te, *ce;
  const void *fcw[5], *fcb[5];
  const void *w[5],  *wb[5];
  const void *g[4],  *be[4];
  float* t;   // d_ws: t[0..31], dtype flag at ((int*)t)[32]
};

// wl layout: fcw[FCIN*16] | fcb[16] | Wpanel[(INC+16)*OUT] | wb[OUT] | g[OUT] | be[OUT]
template<int INC, int OUT, int FCIN, int IS>
__device__ __forceinline__ void do_level(
    int tid, int isbf, const float* curin, float* curout,
    float* cont, const float* cat, float* A, float* Bv,
    unsigned short* wl,
    const void* fcw, const void* fcb, const void* W, const void* Wb,
    const void* g, const void* be)
{
  constexpr int OFF_FCB = FCIN * 16;
  constexpr int OFF_W   = OFF_FCB + 16;          // multiple of 8 shorts (16B)
  constexpr int OFF_WB  = OFF_W + (INC + 16) * OUT;
  constexpr int OFF_G   = OFF_WB + OUT;
  constexpr int OFF_BE  = OFF_G + OUT;

  stage_us(wl,           fcw, FCIN * 16, isbf, tid);
  stage_us(wl + OFF_FCB, fcb, 16,        isbf, tid);
  stageW<OUT, INC + 16>(wl + OFF_W, W, isbf, tid);
  stage_us(wl + OFF_WB,  Wb,  OUT, isbf, tid);
  stage_us(wl + OFF_G,   g,   OUT, isbf, tid);
  stage_us(wl + OFF_BE,  be,  OUT, isbf, tid);
  __syncthreads();

  // contents[n][c] = cat[n,:FCIN] @ fcw + fcb ; thread = (n, 4-col group)
  for (int i = tid; i < 128; i += NT) {
    int n = i >> 2, cg = i & 3;
    float a0 = bs2f(wl[OFF_FCB + 4 * cg]);
    float a1 = bs2f(wl[OFF_FCB + 4 * cg + 1]);
    float a2 = bs2f(wl[OFF_FCB + 4 * cg + 2]);
    float a3 = bs2f(wl[OFF_FCB + 4 * cg + 3]);
    const float4* catp = (const float4*)(cat + n * 52);
#pragma unroll
    for (int k4 = 0; k4 < FCIN / 4; k4++) {
      float4 cv = catp[k4];
      float xs[4] = {cv.x, cv.y, cv.z, cv.w};
#pragma unroll
      for (int j = 0; j < 4; j++) {
        uint2 u = *(const uint2*)(wl + (4 * k4 + j) * 16 + 4 * cg);
        a0 += xs[j] * lo16(u.x); a1 += xs[j] * hi16(u.x);
        a2 += xs[j] * lo16(u.y); a3 += xs[j] * hi16(u.y);
      }
    }
    *(float4*)(cont + n * 20 + 4 * cg) = make_float4(a0, a1, a2, a3);
  }
  __syncthreads();

  // h = leaky(W @ [cur; cont] + wb), 2x2 (n x o) tile, panel b128 weight reads
  constexpr int TO = OUT / 2;
  const uint4* Wp = (const uint4*)(wl + OFF_W);   // [c4][o-pair] uint4
  for (int i = tid; i < 16 * TO; i += NT) {
    int tn = i / TO, to = i % TO;
    int n0 = 2 * tn, o0 = 2 * to;
    const float4* X0 = (const float4*)(curin + n0 * IS);
    const float4* X1 = (const float4*)(curin + (n0 + 1) * IS);
    const float4* C0 = (const float4*)(cont + n0 * 20);
    const float4* C1 = (const float4*)(cont + (n0 + 1) * 20);
    float b0 = bs2f(wl[OFF_WB + o0]), b1 = bs2f(wl[OFF_WB + o0 + 1]);
    float s00 = b0, s01 = b1, s10 = b0, s11 = b1;
#pragma unroll 8
    for (int c4 = 0; c4 < INC / 4; c4++) {
      float4 xa = X0[c4], xb = X1[c4];
      uint4 u = Wp[c4 * (OUT / 2) + to];
      float wa0 = lo16(u.x), wa1 = hi16(u.x), wa2 = lo16(u.y), wa3 = hi16(u.y);
      float wb0 = lo16(u.z), wb1 = hi16(u.z), wb2 = lo16(u.w), wb3 = hi16(u.w);
      s00 += xa.x * wa0 + xa.y * wa1 + xa.z * wa2 + xa.w * wa3;
      s01 += xa.x * wb0 + xa.y * wb1 + xa.z * wb2 + xa.w * wb3;
      s10 += xb.x * wa0 + xb.y * wa1 + xb.z * wa2 + xb.w * wa3;
      s11 += xb.x * wb0 + xb.y * wb1 + xb.z * wb2 + xb.w * wb3;
    }
#pragma unroll
    for (int k4 = 0; k4 < 4; k4++) {
      float4 xa = C0[k4], xb = C1[k4];
      uint4 u = Wp[(INC / 4 + k4) * (OUT / 2) + to];
      float wa0 = lo16(u.x), wa1 = hi16(u.x), wa2 = lo16(u.y), wa3 = hi16(u.y);
      float wb0 = lo16(u.z), wb1 = hi16(u.z), wb2 = lo16(u.w), wb3 = hi16(u.w);
      s00 += xa.x * wa0 + xa.y * wa1 + xa.z * wa2 + xa.w * wa3;
      s01 += xa.x * wb0 + xa.y * wb1 + xa.z * wb2 + xa.w * wb3;
      s10 += xb.x * wa0 + xb.y * wa1 + xb.z * wa2 + xb.w * wa3;
      s11 += xb.x * wb0 + xb.y * wb1 + xb.z * wb2 + xb.w * wb3;
    }
    s00 = s00 >= 0.f ? s00 : 0.2f * s00;
    s01 = s01 >= 0.f ? s01 : 0.2f * s01;
    s10 = s10 >= 0.f ? s10 : 0.2f * s10;
    s11 = s11 >= 0.f ? s11 : 0.2f * s11;
    curout[n0 * 68 + o0]           = s00;
    curout[n0 * 68 + o0 + 1]       = s01;
    curout[(n0 + 1) * 68 + o0]     = s10;
    curout[(n0 + 1) * 68 + o0 + 1] = s11;
  }
  __syncthreads();

  // BN over n (population var), in-place
  if (tid < OUT) {
    int o = tid;
    float su = 0.f, sq = 0.f;
#pragma unroll
    for (int n = 0; n < 32; n++) { float v = curout[n * 68 + o]; su += v; sq += v * v; }
    float mean = su * (1.f / 32.f);
    float var  = fmaxf(sq * (1.f / 32.f) - mean * mean, 0.f);
    float inv  = rsqrtf(var + 1e-5f);
    float a = bs2f(wl[OFF_G + o]) * inv;
    A[o]  = a;
    Bv[o] = bs2f(wl[OFF_BE + o]) - mean * a;
  }
  __syncthreads();
  for (int i = tid; i < 32 * OUT; i += NT) {
    int n = i / OUT, o = i % OUT;
    curout[n * 68 + o] = A[o] * curout[n * 68 + o] + Bv[o];
  }
  __syncthreads();
}

__global__ __launch_bounds__(NT) void head_kernel(Params P) {
  __shared__ __align__(16) float zl[32 * 128];
  __shared__ __align__(16) float cat[32 * 52];
  __shared__ __align__(16) float cont[32 * 20];
  __shared__ __align__(16) float act0[32 * 68];
  __shared__ __align__(16) float act1[32 * 68];
  __shared__ float A[64], Bv[64];
  __shared__ __align__(16) unsigned short wl[9680];
  __shared__ int sOK;
  int tid = threadIdx.x;

  if (tid == 0) sOK = 1;
  __syncthreads();
  if (tid < 64) {
    unsigned int w = ((const unsigned int*)P.z)[tid];
    float a = fabsf(bs2f((unsigned short)(w & 0xFFFFu)));
    if (!(a == 0.0f || (a >= 1e-12f && a <= 1e4f))) atomicAnd(&sOK, 0);
  }
  __syncthreads();
  const int isbf = sOK;
  if (tid == 0) ((int*)P.t)[32] = isbf;

  // stage z (f32 in LDS) vectorized
  if (isbf) {
    const uint4* s = (const uint4*)P.z;           // 8 bf16 per uint4
    for (int j = tid; j < 512; j += NT) {
      uint4 u = s[j];
      float4 lo = make_float4(lo16(u.x), hi16(u.x), lo16(u.y), hi16(u.y));
      float4 hi = make_float4(lo16(u.z), hi16(u.z), lo16(u.w), hi16(u.w));
      *(float4*)(zl + 8 * j)     = lo;
      *(float4*)(zl + 8 * j + 4) = hi;
    }
  } else {
    const float4* s = (const float4*)P.z;
    for (int j = tid; j < 1024; j += NT) *(float4*)(zl + 4 * j) = s[j];
  }
  for (int i = tid; i < 512; i += NT) {
    int n = i >> 4, c = i & 15;
    cat[n * 52 + c]      = gld(P.se, P.sv[n] * 16 + c, isbf);
    cat[n * 52 + 16 + c] = gld(P.te, P.tv[n] * 16 + c, isbf);
    cat[n * 52 + 32 + c] = gld(P.ce, P.cv[n] * 16 + c, isbf);
  }
  // (first do_level syncs after staging, before any zl/cat read)

  do_level<128, 64, 16, 128>(tid, isbf, zl,   act0, cont, cat, A, Bv, wl,
      P.fcw[0], P.fcb[0], P.w[0], P.wb[0], P.g[0], P.be[0]);
  do_level< 64, 32, 32,  68>(tid, isbf, act0, act1, cont, cat, A, Bv, wl,
      P.fcw[1], P.fcb[1], P.w[1], P.wb[1], P.g[1], P.be[1]);
  do_level< 32, 16, 48,  68>(tid, isbf, act1, act0, cont, cat, A, Bv, wl,
      P.fcw[2], P.fcb[2], P.w[2], P.wb[2], P.g[2], P.be[2]);
  do_level< 16,  8, 48,  68>(tid, isbf, act0, act1, cont, cat, A, Bv, wl,
      P.fcw[3], P.fcb[3], P.w[3], P.wb[3], P.g[3], P.be[3]);

  // level 4: contents via fc4 (48-in), OUT=1, tanh, no BN
  stage_us(wl,       P.fcw[4], 768, isbf, tid);
  stage_us(wl + 768, P.fcb[4], 16,  isbf, tid);
  stage_us(wl + 784, P.w[4],   24,  isbf, tid);
  stage_us(wl + 808, P.wb[4],  1,   isbf, tid);
  __syncthreads();
  for (int i = tid; i < 128; i += NT) {
    int n = i >> 2, cg = i & 3;
    float a0 = bs2f(wl[768 + 4 * cg]);
    float a1 = bs2f(wl[768 + 4 * cg + 1]);
    float a2 = bs2f(wl[768 + 4 * cg + 2]);
    float a3 = bs2f(wl[768 + 4 * cg + 3]);
    const float4* catp = (const float4*)(cat + n * 52);
#pragma unroll
    for (int k4 = 0; k4 < 12; k4++) {
      float4 cv = catp[k4];
      float xs[4] = {cv.x, cv.y, cv.z, cv.w};
#pragma unroll
      for (int j = 0; j < 4; j++) {
        uint2 u = *(const uint2*)(wl + (4 * k4 + j) * 16 + 4 * cg);
        a0 += xs[j] * lo16(u.x); a1 += xs[j] * hi16(u.x);
        a2 += xs[j] * lo16(u.y); a3 += xs[j] * hi16(u.y);
      }
    }
    *(float4*)(cont + n * 20 + 4 * cg) = make_float4(a0, a1, a2, a3);
  }
  __syncthreads();
  if (tid < 32) {
    int n = tid;
    float s = bs2f(wl[808]);
#pragma unroll
    for (int c = 0; c < 8; c++) s += act1[n * 68 + c] * bs2f(wl[784 + c]);
#pragma unroll
    for (int k = 0; k < 16; k++) s += cont[n * 20 + k] * bs2f(wl[784 + 8 + k]);
    P.t[n] = tanhf(s);
  }
}

// out[n*ROW + j] = t[n] for all j, in the detected output dtype.
__global__ __launch_bounds__(256) void bcast_kernel(const float* __restrict__ t,
                                                    void* __restrict__ outv) {
  int n = blockIdx.y;
  int isbf = ((const int*)t)[32];
  float tv = t[n];
  int chunk = blockIdx.x * 256 + threadIdx.x;

  if (isbf) {
    unsigned short us = f2bs(tv);
    unsigned int u2 = ((unsigned int)us << 16) | (unsigned int)us;
    uint4 v4 = make_uint4(u2, u2, u2, u2);
    unsigned short* row = (unsigned short*)outv + (size_t)n * ROW;
    int s = (int)((16u - ((unsigned int)(unsigned long long)row & 15u)) & 15u) >> 1;
    int e = s + chunk * 8;
    if (e + 8 <= ROW) *(uint4*)(row + e) = v4;
    if (blockIdx.x == 0 && threadIdx.x == 0) {
      for (int i = 0; i < s; i++) row[i] = us;
      int nch = (ROW - s) >> 3;
      for (int i = s + nch * 8; i < ROW; i++) row[i] = us;
    }
  } else {
    float* row = (float*)outv + (size_t)n * ROW;
    int s = (int)((16u - ((unsigned int)(unsigned long long)row & 15u)) & 15u) >> 2;
    int e = s + chunk * 4;
    if (e + 4 <= ROW) *(float4*)(row + e) = make_float4(tv, tv, tv, tv);
    if (blockIdx.x == 0 && threadIdx.x == 0) {
      for (int i = 0; i < s; i++) row[i] = tv;
      int nch = (ROW - s) >> 2;
      for (int i = s + nch * 4; i < ROW; i++) row[i] = tv;
    }
  }
}

extern "C" void kernel_launch(void* const* d_in, const int* in_sizes, int n_in,
                              void* d_out, int out_size, void* d_ws, size_t ws_size,
                              hipStream_t stream) {
  Params P;
  P.z  = d_in[0];
  P.sv = (const int*)d_in[1];
  P.tv = (const int*)d_in[2];
  P.cv = (const int*)d_in[3];
  P.se = d_in[4];
  P.te = d_in[5];
  P.ce = d_in[6];
  for (int i = 0; i < 5; i++) {
    P.fcw[i] = d_in[7 + 2 * i];
    P.fcb[i] = d_in[8 + 2 * i];
  }
  for (int i = 0; i < 5; i++) {
    P.w[i]  = d_in[17 + 2 * i];
    P.wb[i] = d_in[18 + 2 * i];
  }
  for (int i = 0; i < 4; i++) {
    P.g[i]  = d_in[27 + 2 * i];
    P.be[i] = d_in[28 + 2 * i];
  }
  // p0..p4 (d_in[35..39]) are provably dead (node axis carries no information).
  P.t = (float*)d_ws;

  hipLaunchKernelGGL(head_kernel, dim3(1), dim3(NT), 0, stream, P);
  // grid.x = 67 covers f32 (ceil(67615/4/256)); bf16 needs 34, extras guarded out.
  hipLaunchKernelGGL(bcast_kernel, dim3(67, 32), dim3(256), 0, stream,
                     (const float*)d_ws, d_out);
}